// Round 1
// baseline (277.366 us; speedup 1.0000x reference)
//
#include <hip/hip_runtime.h>
#include <cmath>
#include <cstdint>

#define NLEVELS 16
#define LOG2T 19
#define TSIZE (1u << LOG2T)

struct ResTable { float r[NLEVELS]; };

__global__ __launch_bounds__(256) void ngp_fused(
    const float* __restrict__ x,        // (N,3)
    const float* __restrict__ d,        // (N,3)
    const float* __restrict__ table,    // (L,T,2)
    const float* __restrict__ xyz_w0,   // (64,32)
    const float* __restrict__ xyz_wout, // (16,64)
    const float* __restrict__ rgb_w0,   // (64,32)
    const float* __restrict__ rgb_w1,   // (64,64)
    const float* __restrict__ rgb_wout, // (3,64)
    float* __restrict__ out,            // [N] sigma then [N*3] rgb
    ResTable res, int n)
{
    int i = blockIdx.x * blockDim.x + threadIdx.x;
    if (i >= n) return;

    // ---- normalize position to [0,1] (SCALE=0.5 -> xn = x + 0.5, /1.0 exact)
    float xn0 = x[3 * i + 0] + 0.5f;
    float xn1 = x[3 * i + 1] + 0.5f;
    float xn2 = x[3 * i + 2] + 0.5f;

    // ---- multires hash encode: emb[32]
    float emb[NLEVELS * 2];
    #pragma unroll
    for (int l = 0; l < NLEVELS; ++l) {
        float r  = res.r[l];
        float p0 = xn0 * r, p1 = xn1 * r, p2 = xn2 * r;
        float f0 = floorf(p0), f1 = floorf(p1), f2 = floorf(p2);
        float fr0 = p0 - f0, fr1 = p1 - f1, fr2 = p2 - f2;
        uint32_t xi0 = (uint32_t)f0, xi1 = (uint32_t)f1, xi2 = (uint32_t)f2;
        // per-axis hashed coords for offset 0 and 1 (primes: 1, 2654435761, 805459861)
        uint32_t hx0 = xi0,                       hx1 = xi0 + 1u;
        uint32_t hy0 = xi1 * 2654435761u,         hy1 = (xi1 + 1u) * 2654435761u;
        uint32_t hz0 = xi2 * 805459861u,          hz1 = (xi2 + 1u) * 805459861u;
        const float* tl = table + (size_t)l * (size_t)TSIZE * 2u;
        float acc0 = 0.f, acc1 = 0.f;
        #pragma unroll
        for (int c = 0; c < 8; ++c) {
            // offs order: i (x) major, k (z) minor -> c&4 = x-offset, c&2 = y, c&1 = z
            uint32_t hx = (c & 4) ? hx1 : hx0;
            uint32_t hy = (c & 2) ? hy1 : hy0;
            uint32_t hz = (c & 1) ? hz1 : hz0;
            uint32_t h  = (hx ^ hy ^ hz) & (TSIZE - 1u);
            float wx = (c & 4) ? fr0 : 1.f - fr0;
            float wy = (c & 2) ? fr1 : 1.f - fr1;
            float wz = (c & 1) ? fr2 : 1.f - fr2;
            float w  = wx * wy * wz;
            float2 v = *reinterpret_cast<const float2*>(tl + 2u * h);
            acc0 = fmaf(w, v.x, acc0);
            acc1 = fmaf(w, v.y, acc1);
        }
        emb[2 * l]     = acc0;
        emb[2 * l + 1] = acc1;
    }

    // ---- xyz MLP: 32 -> 64 (ReLU) -> 16 (linear)
    float h1[64];
    #pragma unroll
    for (int j = 0; j < 64; ++j) {
        float s = 0.f;
        #pragma unroll
        for (int k = 0; k < 32; ++k) s = fmaf(emb[k], xyz_w0[j * 32 + k], s);
        h1[j] = fmaxf(s, 0.f);
    }
    float hh[16];
    #pragma unroll
    for (int o = 0; o < 16; ++o) {
        float s = 0.f;
        #pragma unroll
        for (int k = 0; k < 64; ++k) s = fmaf(h1[k], xyz_wout[o * 64 + k], s);
        hh[o] = s;
    }
    out[i] = expf(hh[0]);   // sigma

    // ---- SH degree-4 encode of normalized direction
    float dx = d[3 * i + 0], dy = d[3 * i + 1], dz = d[3 * i + 2];
    float inv = rsqrtf(dx * dx + dy * dy + dz * dz);
    float X = dx * inv, Y = dy * inv, Z = dz * inv;
    float xx = X * X, yy = Y * Y, zz = Z * Z;
    float xy = X * Y, yz = Y * Z, xz = X * Z;

    float f[32];
    f[0]  = 0.28209479177387814f;
    f[1]  = -0.4886025119029199f * Y;
    f[2]  =  0.4886025119029199f * Z;
    f[3]  = -0.4886025119029199f * X;
    f[4]  =  1.0925484305920792f * xy;
    f[5]  = -1.0925484305920792f * yz;
    f[6]  =  0.31539156525252005f * (3.0f * zz - 1.0f);
    f[7]  = -1.0925484305920792f * xz;
    f[8]  =  0.5462742152960396f * (xx - yy);
    f[9]  = -0.5900435899266435f * Y * (3.0f * xx - yy);
    f[10] =  2.890611442640554f * xy * Z;
    f[11] = -0.4570457994644658f * Y * (4.0f * zz - xx - yy);
    f[12] =  0.3731763325901154f * Z * (2.0f * zz - 3.0f * xx - 3.0f * yy);
    f[13] = -0.4570457994644658f * X * (4.0f * zz - xx - yy);
    f[14] =  1.445305721320277f * Z * (xx - yy);
    f[15] = -0.5900435899266435f * X * (xx - 3.0f * yy);
    #pragma unroll
    for (int o = 0; o < 16; ++o) f[16 + o] = hh[o];

    // ---- rgb MLP: 32 -> 64 (ReLU) -> 64 (ReLU) -> 3 (sigmoid)
    float b1[64];
    #pragma unroll
    for (int j = 0; j < 64; ++j) {
        float s = 0.f;
        #pragma unroll
        for (int k = 0; k < 32; ++k) s = fmaf(f[k], rgb_w0[j * 32 + k], s);
        b1[j] = fmaxf(s, 0.f);
    }
    float b2[64];
    #pragma unroll
    for (int j = 0; j < 64; ++j) {
        float s = 0.f;
        #pragma unroll
        for (int k = 0; k < 64; ++k) s = fmaf(b1[k], rgb_w1[j * 64 + k], s);
        b2[j] = fmaxf(s, 0.f);
    }
    #pragma unroll
    for (int o = 0; o < 3; ++o) {
        float s = 0.f;
        #pragma unroll
        for (int k = 0; k < 64; ++k) s = fmaf(b2[k], rgb_wout[o * 64 + k], s);
        out[n + 3 * i + o] = 1.0f / (1.0f + expf(-s));
    }
}

extern "C" void kernel_launch(void* const* d_in, const int* in_sizes, int n_in,
                              void* d_out, int out_size, void* d_ws, size_t ws_size,
                              hipStream_t stream) {
    const float* x        = (const float*)d_in[0];
    const float* d        = (const float*)d_in[1];
    const float* table    = (const float*)d_in[2];
    const float* xyz_w0   = (const float*)d_in[3];
    const float* xyz_wout = (const float*)d_in[4];
    const float* rgb_w0   = (const float*)d_in[5];
    const float* rgb_w1   = (const float*)d_in[6];
    const float* rgb_wout = (const float*)d_in[7];
    float* out = (float*)d_out;

    int n = in_sizes[0] / 3;

    // resolution table computed in float64 exactly like numpy (level 14 is
    // 1482.0045 -- device-f32 recompute could floor to 1481 and corrupt hashes)
    ResTable rt;
    double b = std::exp((std::log(2048.0) - std::log(16.0)) / 15.0);
    for (int l = 0; l < NLEVELS; ++l)
        rt.r[l] = (float)std::floor(16.0 * std::pow(b, (double)l));

    int blocks = (n + 255) / 256;
    hipLaunchKernelGGL(ngp_fused, dim3(blocks), dim3(256), 0, stream,
                       x, d, table, xyz_w0, xyz_wout, rgb_w0, rgb_w1, rgb_wout,
                       out, rt, n);
}